// Round 1
// baseline (1046.557 us; speedup 1.0000x reference)
//
#include <hip/hip_runtime.h>

// Swin block, MI355X. Constants hard-coded: B=4, H=W=192, C=256, HEADS=8, hd=32,
// WIN=8, SHIFT=4, HID=1024. 192%8==0 -> no pad; reference applies no shift mask.
// I/O fp32; internal GEMMs bf16 MFMA (16x16x32), fp32 accum.
// Workspace layout (needs ~380 MB):
//   [0,384K)        qkv_w^T bf16 (768x256)
//   [384K,512K)     proj_w^T bf16 (256x256)
//   [512K,1M)       fc1_w^T bf16 (1024x256)
//   [1M,1.5M)       fc2_w^T bf16 (256x1024)
//   hbuf  75.5MB    LN1 out (window order) -> reused as attn-out -> reused as LN2 out
//   big   302MB     qkv (147456x768 bf16)  -> reused as fc1 hidden (147456x1024 bf16)

#define SHIFT_ 4

typedef __attribute__((ext_vector_type(8))) short short8;
typedef __attribute__((ext_vector_type(4))) float floatx4;

__device__ __forceinline__ float b2f(unsigned short u) {
  union { unsigned int i; float f; } c; c.i = ((unsigned int)u) << 16; return c.f;
}
__device__ __forceinline__ unsigned short f2b(float f) {
  union { float f; unsigned int i; } c; c.f = f;
  unsigned int u = c.i;
  return (unsigned short)((u + 0x7FFFu + ((u >> 16) & 1u)) >> 16);
}

__device__ __forceinline__ void load_lds16(const void* g, void* l) {
  __builtin_amdgcn_global_load_lds((__attribute__((address_space(1))) void*)g,
                                   (__attribute__((address_space(3))) void*)l, 16, 0, 0);
}

// window-order row -> flat token index (applies roll(+shift) both directions; gather==scatter map)
__device__ __forceinline__ size_t tok_of_row(int row) {
  int widx = row >> 6, t = row & 63;
  int b = widx / 576; int rem = widx - b * 576;
  int wy = rem / 24, wx = rem - wy * 24;
  int ti = t >> 3, tj = t & 7;
  int gr = wy * 8 + ti + SHIFT_; if (gr >= 192) gr -= 192;
  int gc = wx * 8 + tj + SHIFT_; if (gc >= 192) gc -= 192;
  return (size_t)b * 36864 + (size_t)(gr * 192 + gc);
}

// ---- LayerNorm (one wave per token row), optional shifted-window gather ----
template<int SHUFFLE>
__global__ __launch_bounds__(256) void ln_kernel(const float* __restrict__ src,
    const float* __restrict__ gw, const float* __restrict__ bw,
    unsigned short* __restrict__ dst) {
  const int lane = threadIdx.x & 63;
  const int m = blockIdx.x * 4 + (threadIdx.x >> 6);
  const size_t soff = SHUFFLE ? tok_of_row(m) * 256 : (size_t)m * 256;
  float4 xv = *(const float4*)(src + soff + lane * 4);
  float s  = xv.x + xv.y + xv.z + xv.w;
  float s2 = xv.x * xv.x + xv.y * xv.y + xv.z * xv.z + xv.w * xv.w;
  #pragma unroll
  for (int off = 32; off > 0; off >>= 1) { s += __shfl_xor(s, off); s2 += __shfl_xor(s2, off); }
  const float mean = s * 0.00390625f;
  const float var  = s2 * 0.00390625f - mean * mean;
  const float rstd = rsqrtf(var + 1e-5f);
  float4 gv = *(const float4*)(gw + lane * 4);
  float4 bv = *(const float4*)(bw + lane * 4);
  ushort4 o;
  o.x = f2b((xv.x - mean) * rstd * gv.x + bv.x);
  o.y = f2b((xv.y - mean) * rstd * gv.y + bv.y);
  o.z = f2b((xv.z - mean) * rstd * gv.z + bv.z);
  o.w = f2b((xv.w - mean) * rstd * gv.w + bv.w);
  *(ushort4*)(dst + (size_t)m * 256 + lane * 4) = o;
}

// ---- weight transpose fp32 KxN -> bf16 NxK (grid covers exactly N*K threads) ----
__global__ void wconv(const float* __restrict__ W, unsigned short* __restrict__ Wt,
                      int K, int N) {
  const int idx = blockIdx.x * 256 + threadIdx.x;
  const int n = idx / K, k = idx - n * K;
  Wt[idx] = f2b(W[(size_t)k * N + n]);
}

// ---- GEMM C[M,N] = A[M,K] @ Wt[N,K]^T, m97 structure. MODE epilogues:
// 0: out bf16 = C + bias            (QKV)
// 1: out f32  = X + C + bias, window->token scatter (proj + residual)
// 2: out bf16 = gelu(C + bias)      (FC1)
// 3: out f32  = X + C + bias        (FC2 + residual)
template<int MODE>
__global__ __launch_bounds__(256) void gemm_bt(
    const unsigned short* __restrict__ A, const unsigned short* __restrict__ Wt,
    const float* __restrict__ bias, const float* __restrict__ X,
    unsigned short* __restrict__ outb, float* __restrict__ outf,
    int Ntot, int K) {
  __shared__ unsigned short sm[8192];           // A tile 128x32 | B tile 128x32
  const int tid = threadIdx.x;
  const int wave = tid >> 6, lane = tid & 63;
  const int lr = lane & 15, lg = lane >> 4;
  const int wm = wave >> 1, wn = wave & 1;
  const int m0 = blockIdx.y * 128, n0 = blockIdx.x * 128;
  floatx4 acc[4][4];
  #pragma unroll
  for (int i = 0; i < 4; ++i)
    #pragma unroll
    for (int j = 0; j < 4; ++j) acc[i][j] = (floatx4)0.f;

  for (int k0 = 0; k0 < K; k0 += 32) {
    __syncthreads();
    #pragma unroll
    for (int t = 0; t < 4; ++t) {
      const int chunk = wave * 4 + t;           // 0..15, wave-uniform
      const int eoff = chunk * 512 + lane * 8;  // bf16 element offset in 8192
      const unsigned short* gp;
      if (chunk < 8) {                          // A region
        const int r = eoff >> 5, c = eoff & 31;
        gp = A + (size_t)(m0 + r) * K + (k0 + c);
      } else {                                  // B region
        const int e = eoff - 4096;
        const int r = e >> 5, c = e & 31;
        gp = Wt + (size_t)(n0 + r) * K + (k0 + c);
      }
      load_lds16(gp, &sm[chunk * 512]);         // lds base wave-uniform; HW adds lane*16B
    }
    __syncthreads();
    short8 af[4], bf[4];
    #pragma unroll
    for (int mi = 0; mi < 4; ++mi)
      af[mi] = *(const short8*)&sm[(wm * 64 + mi * 16 + lr) * 32 + lg * 8];
    #pragma unroll
    for (int ni = 0; ni < 4; ++ni)
      bf[ni] = *(const short8*)&sm[4096 + (wn * 64 + ni * 16 + lr) * 32 + lg * 8];
    #pragma unroll
    for (int mi = 0; mi < 4; ++mi)
      #pragma unroll
      for (int ni = 0; ni < 4; ++ni)
        acc[mi][ni] = __builtin_amdgcn_mfma_f32_16x16x32_bf16(af[mi], bf[ni], acc[mi][ni], 0, 0, 0);
  }

  #pragma unroll
  for (int mi = 0; mi < 4; ++mi) {
    #pragma unroll
    for (int r = 0; r < 4; ++r) {
      const int row = m0 + wm * 64 + mi * 16 + lg * 4 + r;
      size_t obase;
      if (MODE == 1) obase = tok_of_row(row) * 256;
      else obase = (size_t)row * Ntot;
      #pragma unroll
      for (int ni = 0; ni < 4; ++ni) {
        const int col = n0 + wn * 64 + ni * 16 + lr;
        const float v = acc[mi][ni][r] + bias[col];
        if (MODE == 0) {
          outb[obase + col] = f2b(v);
        } else if (MODE == 1) {
          outf[obase + col] = X[obase + col] + v;
        } else if (MODE == 2) {
          outb[obase + col] = f2b(0.5f * v * (1.f + erff(v * 0.70710678f)));
        } else {
          outf[obase + col] = X[obase + col] + v;
        }
      }
    }
  }
}

// ---- attention: one wave per (window, head). qkv rows are [3][8][32] packed. ----
__global__ __launch_bounds__(64) void attn_kernel(const unsigned short* __restrict__ qkv,
    const float* __restrict__ btab, unsigned short* __restrict__ obuf) {
  __shared__ unsigned short qs[2048];   // 64 x 32
  __shared__ unsigned short ks[2048];   // 64 x 32
  __shared__ unsigned short vts[2048];  // 32 x 64 (v transposed)
  __shared__ unsigned short ps[4096];   // 64 x 64 probabilities bf16
  __shared__ float bs[225];
  const int l = threadIdx.x;
  const int win = blockIdx.x >> 3, head = blockIdx.x & 7;
  const int lr = l & 15, lg = l >> 4;
  const unsigned short* base = qkv + (size_t)(win * 64 + l) * 768 + head * 32;
  #pragma unroll
  for (int c = 0; c < 4; ++c) {
    *(uint4*)&qs[l * 32 + c * 8] = *(const uint4*)(base + c * 8);
    *(uint4*)&ks[l * 32 + c * 8] = *(const uint4*)(base + 256 + c * 8);
  }
  #pragma unroll
  for (int c = 0; c < 8; ++c) {
    ushort4 vv = *(const ushort4*)(base + 512 + c * 4);
    vts[(c * 4 + 0) * 64 + l] = vv.x;
    vts[(c * 4 + 1) * 64 + l] = vv.y;
    vts[(c * 4 + 2) * 64 + l] = vv.z;
    vts[(c * 4 + 3) * 64 + l] = vv.w;
  }
  for (int i = l; i < 225; i += 64) bs[i] = btab[i * 8 + head];
  __syncthreads();

  // S = q @ k^T  (M=64,N=64,K=32)
  short8 af[4], bfr[4];
  #pragma unroll
  for (int mi = 0; mi < 4; ++mi) af[mi] = *(const short8*)&qs[(mi * 16 + lr) * 32 + lg * 8];
  #pragma unroll
  for (int ni = 0; ni < 4; ++ni) bfr[ni] = *(const short8*)&ks[(ni * 16 + lr) * 32 + lg * 8];
  floatx4 sa[4][4];
  #pragma unroll
  for (int mi = 0; mi < 4; ++mi)
    #pragma unroll
    for (int ni = 0; ni < 4; ++ni)
      sa[mi][ni] = __builtin_amdgcn_mfma_f32_16x16x32_bf16(af[mi], bfr[ni], (floatx4)0.f, 0, 0, 0);

  const float scale = 0.17677669529663687f;  // 32^-0.5
  #pragma unroll
  for (int mi = 0; mi < 4; ++mi) {
    #pragma unroll
    for (int r = 0; r < 4; ++r) {
      const int qi = mi * 16 + lg * 4 + r;
      const int ti = qi >> 3, tj = qi & 7;
      float vals[4];
      #pragma unroll
      for (int ni = 0; ni < 4; ++ni) {
        const int kc = ni * 16 + lr;
        const int tk = kc >> 3, tl = kc & 7;
        vals[ni] = sa[mi][ni][r] * scale + bs[(ti - tk + 7) * 15 + (tj - tl + 7)];
      }
      float mx = fmaxf(fmaxf(vals[0], vals[1]), fmaxf(vals[2], vals[3]));
      #pragma unroll
      for (int off = 1; off < 16; off <<= 1) mx = fmaxf(mx, __shfl_xor(mx, off, 16));
      float se = 0.f;
      #pragma unroll
      for (int ni = 0; ni < 4; ++ni) { vals[ni] = __expf(vals[ni] - mx); se += vals[ni]; }
      #pragma unroll
      for (int off = 1; off < 16; off <<= 1) se += __shfl_xor(se, off, 16);
      const float inv = 1.f / se;
      #pragma unroll
      for (int ni = 0; ni < 4; ++ni) ps[qi * 64 + ni * 16 + lr] = f2b(vals[ni] * inv);
    }
  }
  __syncthreads();

  // O = P @ v  (M=64,N=32,K=64)
  floatx4 oa[4][2];
  #pragma unroll
  for (int mi = 0; mi < 4; ++mi) { oa[mi][0] = (floatx4)0.f; oa[mi][1] = (floatx4)0.f; }
  #pragma unroll
  for (int kk = 0; kk < 2; ++kk) {
    short8 pa[4], vb[2];
    #pragma unroll
    for (int mi = 0; mi < 4; ++mi) pa[mi] = *(const short8*)&ps[(mi * 16 + lr) * 64 + kk * 32 + lg * 8];
    #pragma unroll
    for (int nj = 0; nj < 2; ++nj) vb[nj] = *(const short8*)&vts[(nj * 16 + lr) * 64 + kk * 32 + lg * 8];
    #pragma unroll
    for (int mi = 0; mi < 4; ++mi)
      #pragma unroll
      for (int nj = 0; nj < 2; ++nj)
        oa[mi][nj] = __builtin_amdgcn_mfma_f32_16x16x32_bf16(pa[mi], vb[nj], oa[mi][nj], 0, 0, 0);
  }
  #pragma unroll
  for (int mi = 0; mi < 4; ++mi)
    #pragma unroll
    for (int nj = 0; nj < 2; ++nj)
      #pragma unroll
      for (int r = 0; r < 4; ++r) {
        const int row = mi * 16 + lg * 4 + r, d = nj * 16 + lr;
        obuf[(size_t)(win * 64 + row) * 256 + head * 32 + d] = f2b(oa[mi][nj][r]);
      }
}

extern "C" void kernel_launch(void* const* d_in, const int* in_sizes, int n_in,
                              void* d_out, int out_size, void* d_ws, size_t ws_size,
                              hipStream_t stream) {
  (void)in_sizes; (void)n_in; (void)out_size; (void)ws_size;
  const float* x      = (const float*)d_in[0];
  const float* n1g    = (const float*)d_in[1];
  const float* n1b    = (const float*)d_in[2];
  const float* qkv_w  = (const float*)d_in[3];
  const float* qkv_b  = (const float*)d_in[4];
  const float* btab   = (const float*)d_in[5];
  const float* proj_w = (const float*)d_in[6];
  const float* proj_b = (const float*)d_in[7];
  const float* n2g    = (const float*)d_in[8];
  const float* n2b    = (const float*)d_in[9];
  const float* fc1_w  = (const float*)d_in[10];
  const float* fc1_b  = (const float*)d_in[11];
  const float* fc2_w  = (const float*)d_in[12];
  const float* fc2_b  = (const float*)d_in[13];
  float* out = (float*)d_out;

  char* wsb = (char*)d_ws;
  unsigned short* wqkv  = (unsigned short*)(wsb);
  unsigned short* wproj = (unsigned short*)(wsb + 393216);
  unsigned short* wfc1  = (unsigned short*)(wsb + 524288);
  unsigned short* wfc2  = (unsigned short*)(wsb + 1048576);
  unsigned short* hbuf  = (unsigned short*)(wsb + 1572864);    // 75.5 MB
  unsigned short* big   = (unsigned short*)(wsb + 77070336);   // 302 MB

  wconv<<<768, 256, 0, stream>>>(qkv_w, wqkv, 256, 768);
  wconv<<<256, 256, 0, stream>>>(proj_w, wproj, 256, 256);
  wconv<<<1024, 256, 0, stream>>>(fc1_w, wfc1, 256, 1024);
  wconv<<<1024, 256, 0, stream>>>(fc2_w, wfc2, 1024, 256);

  // LN1 + roll/window gather -> hbuf (window order, bf16)
  ln_kernel<1><<<36864, 256, 0, stream>>>(x, n1g, n1b, hbuf);
  // QKV: (147456x256)@(256x768) -> big
  gemm_bt<0><<<dim3(6, 1152), 256, 0, stream>>>(hbuf, wqkv, qkv_b, nullptr, big, nullptr, 768, 256);
  // attention per (window, head): big -> hbuf (attn out, window order)
  attn_kernel<<<18432, 64, 0, stream>>>(big, btab, hbuf);
  // proj + window->token scatter + residual: -> d_out (fp32 x1)
  gemm_bt<1><<<dim3(2, 1152), 256, 0, stream>>>(hbuf, wproj, proj_b, x, nullptr, out, 256, 256);
  // LN2: d_out -> hbuf (token order, bf16)
  ln_kernel<0><<<36864, 256, 0, stream>>>(out, n2g, n2b, hbuf);
  // FC1 + exact GELU: (147456x256)@(256x1024) -> big
  gemm_bt<2><<<dim3(8, 1152), 256, 0, stream>>>(hbuf, wfc1, fc1_b, nullptr, big, nullptr, 1024, 256);
  // FC2 + residual: (147456x1024)@(1024x256) + x1 -> d_out
  gemm_bt<3><<<dim3(2, 1152), 256, 0, stream>>>(big, wfc2, fc2_b, out, nullptr, out, 256, 1024);
}

// Round 2
// 970.267 us; speedup vs baseline: 1.0786x; 1.0786x over previous
//
#include <hip/hip_runtime.h>

// Swin block, MI355X. B=4, H=W=192, C=256, HEADS=8, hd=32, WIN=8, SHIFT=4, HID=1024.
// I/O fp32; internal GEMMs bf16 MFMA (16x16x32), fp32 accum.
// R1: GEMM BK=64 + XOR-8 LDS swizzle (kills 8-way frag-read bank conflicts,
//     halves barrier count); attention: direct q/k frag loads, swizzled ps/vts.

#define SHIFT_ 4

typedef __attribute__((ext_vector_type(8))) short short8;
typedef __attribute__((ext_vector_type(4))) float floatx4;

__device__ __forceinline__ unsigned short f2b(float f) {
  union { float f; unsigned int i; } c; c.f = f;
  unsigned int u = c.i;
  return (unsigned short)((u + 0x7FFFu + ((u >> 16) & 1u)) >> 16);
}

__device__ __forceinline__ void load_lds16(const void* g, void* l) {
  __builtin_amdgcn_global_load_lds((__attribute__((address_space(1))) void*)g,
                                   (__attribute__((address_space(3))) void*)l, 16, 0, 0);
}

// window-order row -> flat token index (roll by +shift; gather==scatter map)
__device__ __forceinline__ size_t tok_of_row(int row) {
  int widx = row >> 6, t = row & 63;
  int b = widx / 576; int rem = widx - b * 576;
  int wy = rem / 24, wx = rem - wy * 24;
  int ti = t >> 3, tj = t & 7;
  int gr = wy * 8 + ti + SHIFT_; if (gr >= 192) gr -= 192;
  int gc = wx * 8 + tj + SHIFT_; if (gc >= 192) gc -= 192;
  return (size_t)b * 36864 + (size_t)(gr * 192 + gc);
}

// ---- LayerNorm (one wave per token row), optional shifted-window gather ----
template<int SHUFFLE>
__global__ __launch_bounds__(256) void ln_kernel(const float* __restrict__ src,
    const float* __restrict__ gw, const float* __restrict__ bw,
    unsigned short* __restrict__ dst) {
  const int lane = threadIdx.x & 63;
  const int m = blockIdx.x * 4 + (threadIdx.x >> 6);
  const size_t soff = SHUFFLE ? tok_of_row(m) * 256 : (size_t)m * 256;
  float4 xv = *(const float4*)(src + soff + lane * 4);
  float s  = xv.x + xv.y + xv.z + xv.w;
  float s2 = xv.x * xv.x + xv.y * xv.y + xv.z * xv.z + xv.w * xv.w;
  #pragma unroll
  for (int off = 32; off > 0; off >>= 1) { s += __shfl_xor(s, off); s2 += __shfl_xor(s2, off); }
  const float mean = s * 0.00390625f;
  const float var  = s2 * 0.00390625f - mean * mean;
  const float rstd = rsqrtf(var + 1e-5f);
  float4 gv = *(const float4*)(gw + lane * 4);
  float4 bv = *(const float4*)(bw + lane * 4);
  ushort4 o;
  o.x = f2b((xv.x - mean) * rstd * gv.x + bv.x);
  o.y = f2b((xv.y - mean) * rstd * gv.y + bv.y);
  o.z = f2b((xv.z - mean) * rstd * gv.z + bv.z);
  o.w = f2b((xv.w - mean) * rstd * gv.w + bv.w);
  *(ushort4*)(dst + (size_t)m * 256 + lane * 4) = o;
}

// ---- weight transpose fp32 KxN -> bf16 NxK ----
__global__ void wconv(const float* __restrict__ W, unsigned short* __restrict__ Wt,
                      int K, int N) {
  const int idx = blockIdx.x * 256 + threadIdx.x;
  const int n = idx / K, k = idx - n * K;
  Wt[idx] = f2b(W[(size_t)k * N + n]);
}

// ---- GEMM C[M,N] = A[M,K] @ Wt[N,K]^T. BK=64, XOR-8 swizzled LDS tiles.
// MODE 0: out bf16 = C + bias            (QKV)
// MODE 1: out f32  = X + C + bias, window->token scatter (proj + residual)
// MODE 2: out bf16 = gelu(C + bias)      (FC1)
// MODE 3: out f32  = X + C + bias        (FC2 + residual)
template<int MODE>
__global__ __launch_bounds__(256) void gemm_bt(
    const unsigned short* __restrict__ A, const unsigned short* __restrict__ Wt,
    const float* __restrict__ bias, const float* __restrict__ X,
    unsigned short* __restrict__ outb, float* __restrict__ outf,
    int Ntot, int K) {
  __shared__ unsigned short sm[16384];          // A 128x64 | B 128x64, both swizzled
  const int tid = threadIdx.x;
  const int wave = tid >> 6, lane = tid & 63;
  const int lr = lane & 15, lg = lane >> 4;
  const int wm = wave >> 1, wn = wave & 1;
  const int m0 = blockIdx.y * 128, n0 = blockIdx.x * 128;
  floatx4 acc[4][4];
  #pragma unroll
  for (int i = 0; i < 4; ++i)
    #pragma unroll
    for (int j = 0; j < 4; ++j) acc[i][j] = (floatx4)0.f;

  for (int k0 = 0; k0 < K; k0 += 64) {
    __syncthreads();
    #pragma unroll
    for (int t = 0; t < 8; ++t) {
      const int chunk = wave * 8 + t;           // 0..31, wave-uniform
      const unsigned short* gp;
      if (chunk < 16) {                         // A region: 16 KB, rows of 128B
        const int P = chunk * 64 + lane;        // 16B cell index
        const int r = P >> 3, pc = P & 7, c = pc ^ (r & 7);
        gp = A + (size_t)(m0 + r) * K + (k0 + c * 8);
      } else {                                  // B region
        const int P = chunk * 64 + lane - 1024;
        const int r = P >> 3, pc = P & 7, c = pc ^ (r & 7);
        gp = Wt + (size_t)(n0 + r) * K + (k0 + c * 8);
      }
      load_lds16(gp, &sm[chunk * 512]);
    }
    __syncthreads();
    #pragma unroll
    for (int kk = 0; kk < 2; ++kk) {
      short8 af[4], bf[4];
      #pragma unroll
      for (int mi = 0; mi < 4; ++mi) {
        const int r = wm * 64 + mi * 16 + lr;
        af[mi] = *(const short8*)&sm[r * 64 + (((kk * 4 + lg) ^ (r & 7)) * 8)];
      }
      #pragma unroll
      for (int ni = 0; ni < 4; ++ni) {
        const int r = wn * 64 + ni * 16 + lr;
        bf[ni] = *(const short8*)&sm[8192 + r * 64 + (((kk * 4 + lg) ^ (r & 7)) * 8)];
      }
      #pragma unroll
      for (int mi = 0; mi < 4; ++mi)
        #pragma unroll
        for (int ni = 0; ni < 4; ++ni)
          acc[mi][ni] = __builtin_amdgcn_mfma_f32_16x16x32_bf16(af[mi], bf[ni], acc[mi][ni], 0, 0, 0);
    }
  }

  #pragma unroll
  for (int mi = 0; mi < 4; ++mi) {
    #pragma unroll
    for (int r = 0; r < 4; ++r) {
      const int row = m0 + wm * 64 + mi * 16 + lg * 4 + r;
      size_t obase;
      if (MODE == 1) obase = tok_of_row(row) * 256;
      else obase = (size_t)row * Ntot;
      #pragma unroll
      for (int ni = 0; ni < 4; ++ni) {
        const int col = n0 + wn * 64 + ni * 16 + lr;
        const float v = acc[mi][ni][r] + bias[col];
        if (MODE == 0) {
          outb[obase + col] = f2b(v);
        } else if (MODE == 1) {
          outf[obase + col] = X[obase + col] + v;
        } else if (MODE == 2) {
          outb[obase + col] = f2b(0.5f * v * (1.f + erff(v * 0.70710678f)));
        } else {
          outf[obase + col] = X[obase + col] + v;
        }
      }
    }
  }
}

// ---- attention: one wave per (window, head). qkv rows are [3][8][32] packed.
// q/k fragments loaded directly from global; v^T and P staged in swizzled LDS.
__global__ __launch_bounds__(64) void attn_kernel(const unsigned short* __restrict__ qkv,
    const float* __restrict__ btab, unsigned short* __restrict__ obuf) {
  __shared__ unsigned short vts[2048];  // 32 x 64 (v^T), XOR-8 swizzled cells
  __shared__ unsigned short ps[4096];   // 64 x 64 probabilities, XOR-8 swizzled
  __shared__ float bs[225];
  const int l = threadIdx.x;
  const int win = blockIdx.x >> 3, head = blockIdx.x & 7;
  const int lr = l & 15, lg = l >> 4;
  const unsigned short* base = qkv + (size_t)(win * 64) * 768 + head * 32;

  // stage v^T: logical vts[d][tok], d=0..31, tok=0..63
  #pragma unroll
  for (int c = 0; c < 8; ++c) {
    ushort4 vv = *(const ushort4*)(base + (size_t)l * 768 + 512 + c * 4);
    #pragma unroll
    for (int j = 0; j < 4; ++j) {
      const int d = c * 4 + j;
      const unsigned short val = j == 0 ? vv.x : j == 1 ? vv.y : j == 2 ? vv.z : vv.w;
      vts[d * 64 + (((l >> 3) ^ (d & 7)) * 8) + (l & 7)] = val;
    }
  }
  for (int i = l; i < 225; i += 64) bs[i] = btab[i * 8 + head];

  // q/k fragments directly from global
  short8 af[4], bfr[4];
  #pragma unroll
  for (int mi = 0; mi < 4; ++mi)
    af[mi] = *(const short8*)(base + (size_t)(mi * 16 + lr) * 768 + lg * 8);
  #pragma unroll
  for (int ni = 0; ni < 4; ++ni)
    bfr[ni] = *(const short8*)(base + (size_t)(ni * 16 + lr) * 768 + 256 + lg * 8);

  // S = q @ k^T  (M=64,N=64,K=32)
  floatx4 sa[4][4];
  #pragma unroll
  for (int mi = 0; mi < 4; ++mi)
    #pragma unroll
    for (int ni = 0; ni < 4; ++ni)
      sa[mi][ni] = __builtin_amdgcn_mfma_f32_16x16x32_bf16(af[mi], bfr[ni], (floatx4)0.f, 0, 0, 0);

  __syncthreads();  // vts/bs visible

  const float scale = 0.17677669529663687f;  // 32^-0.5
  #pragma unroll
  for (int mi = 0; mi < 4; ++mi) {
    #pragma unroll
    for (int r = 0; r < 4; ++r) {
      const int qi = mi * 16 + lg * 4 + r;
      const int ti = qi >> 3, tj = qi & 7;
      float vals[4];
      #pragma unroll
      for (int ni = 0; ni < 4; ++ni) {
        const int kc = ni * 16 + lr;
        const int tk = kc >> 3, tl = kc & 7;
        vals[ni] = sa[mi][ni][r] * scale + bs[(ti - tk + 7) * 15 + (tj - tl + 7)];
      }
      float mx = fmaxf(fmaxf(vals[0], vals[1]), fmaxf(vals[2], vals[3]));
      #pragma unroll
      for (int off = 1; off < 16; off <<= 1) mx = fmaxf(mx, __shfl_xor(mx, off, 16));
      float se = 0.f;
      #pragma unroll
      for (int ni = 0; ni < 4; ++ni) { vals[ni] = __expf(vals[ni] - mx); se += vals[ni]; }
      #pragma unroll
      for (int off = 1; off < 16; off <<= 1) se += __shfl_xor(se, off, 16);
      const float inv = 1.f / se;
      #pragma unroll
      for (int ni = 0; ni < 4; ++ni) {
        const int col = ni * 16 + lr;
        const int cell = col >> 3;
        ps[qi * 64 + ((cell ^ (qi & 7)) * 8) + (col & 7)] = f2b(vals[ni] * inv);
      }
    }
  }
  __syncthreads();

  // O = P @ v  (M=64,N=32,K=64)
  floatx4 oa[4][2];
  #pragma unroll
  for (int mi = 0; mi < 4; ++mi) { oa[mi][0] = (floatx4)0.f; oa[mi][1] = (floatx4)0.f; }
  #pragma unroll
  for (int kk = 0; kk < 2; ++kk) {
    short8 pa[4], vb[2];
    #pragma unroll
    for (int mi = 0; mi < 4; ++mi) {
      const int r = mi * 16 + lr;
      pa[mi] = *(const short8*)&ps[r * 64 + (((kk * 4 + lg) ^ (r & 7)) * 8)];
    }
    #pragma unroll
    for (int nj = 0; nj < 2; ++nj) {
      const int r = nj * 16 + lr;
      vb[nj] = *(const short8*)&vts[r * 64 + (((kk * 4 + lg) ^ (r & 7)) * 8)];
    }
    #pragma unroll
    for (int mi = 0; mi < 4; ++mi)
      #pragma unroll
      for (int nj = 0; nj < 2; ++nj)
        oa[mi][nj] = __builtin_amdgcn_mfma_f32_16x16x32_bf16(pa[mi], vb[nj], oa[mi][nj], 0, 0, 0);
  }
  #pragma unroll
  for (int mi = 0; mi < 4; ++mi)
    #pragma unroll
    for (int nj = 0; nj < 2; ++nj)
      #pragma unroll
      for (int r = 0; r < 4; ++r) {
        const int row = mi * 16 + lg * 4 + r, d = nj * 16 + lr;
        obuf[(size_t)(win * 64 + row) * 256 + head * 32 + d] = f2b(oa[mi][nj][r]);
      }
}

extern "C" void kernel_launch(void* const* d_in, const int* in_sizes, int n_in,
                              void* d_out, int out_size, void* d_ws, size_t ws_size,
                              hipStream_t stream) {
  (void)in_sizes; (void)n_in; (void)out_size; (void)ws_size;
  const float* x      = (const float*)d_in[0];
  const float* n1g    = (const float*)d_in[1];
  const float* n1b    = (const float*)d_in[2];
  const float* qkv_w  = (const float*)d_in[3];
  const float* qkv_b  = (const float*)d_in[4];
  const float* btab   = (const float*)d_in[5];
  const float* proj_w = (const float*)d_in[6];
  const float* proj_b = (const float*)d_in[7];
  const float* n2g    = (const float*)d_in[8];
  const float* n2b    = (const float*)d_in[9];
  const float* fc1_w  = (const float*)d_in[10];
  const float* fc1_b  = (const float*)d_in[11];
  const float* fc2_w  = (const float*)d_in[12];
  const float* fc2_b  = (const float*)d_in[13];
  float* out = (float*)d_out;

  char* wsb = (char*)d_ws;
  unsigned short* wqkv  = (unsigned short*)(wsb);
  unsigned short* wproj = (unsigned short*)(wsb + 393216);
  unsigned short* wfc1  = (unsigned short*)(wsb + 524288);
  unsigned short* wfc2  = (unsigned short*)(wsb + 1048576);
  unsigned short* hbuf  = (unsigned short*)(wsb + 1572864);    // 75.5 MB
  unsigned short* big   = (unsigned short*)(wsb + 77070336);   // 302 MB

  wconv<<<768, 256, 0, stream>>>(qkv_w, wqkv, 256, 768);
  wconv<<<256, 256, 0, stream>>>(proj_w, wproj, 256, 256);
  wconv<<<1024, 256, 0, stream>>>(fc1_w, wfc1, 256, 1024);
  wconv<<<1024, 256, 0, stream>>>(fc2_w, wfc2, 1024, 256);

  // LN1 + roll/window gather -> hbuf (window order, bf16)
  ln_kernel<1><<<36864, 256, 0, stream>>>(x, n1g, n1b, hbuf);
  // QKV: (147456x256)@(256x768) -> big
  gemm_bt<0><<<dim3(6, 1152), 256, 0, stream>>>(hbuf, wqkv, qkv_b, nullptr, big, nullptr, 768, 256);
  // attention per (window, head): big -> hbuf (attn out, window order)
  attn_kernel<<<18432, 64, 0, stream>>>(big, btab, hbuf);
  // proj + window->token scatter + residual: -> d_out (fp32 x1)
  gemm_bt<1><<<dim3(2, 1152), 256, 0, stream>>>(hbuf, wproj, proj_b, x, nullptr, out, 256, 256);
  // LN2: d_out -> hbuf (token order, bf16)
  ln_kernel<0><<<36864, 256, 0, stream>>>(out, n2g, n2b, hbuf);
  // FC1 + exact GELU: (147456x256)@(256x1024) -> big
  gemm_bt<2><<<dim3(8, 1152), 256, 0, stream>>>(hbuf, wfc1, fc1_b, nullptr, big, nullptr, 1024, 256);
  // FC2 + residual: (147456x1024)@(1024x256) + x1 -> d_out
  gemm_bt<3><<<dim3(2, 1152), 256, 0, stream>>>(big, wfc2, fc2_b, out, nullptr, out, 256, 1024);
}